// Round 1
// baseline (426.684 us; speedup 1.0000x reference)
//
#include <hip/hip_runtime.h>
#include <hip/hip_bf16.h>

#define HH 1024
#define FF 4096
#define MTOT (8 * 2048)

typedef __attribute__((ext_vector_type(4))) float f32x4;
typedef __attribute__((ext_vector_type(8))) short bf16x8;

__device__ inline void async_load16(const void* g, void* l) {
    __builtin_amdgcn_global_load_lds(
        (const __attribute__((address_space(1))) unsigned int*)g,
        (__attribute__((address_space(3))) unsigned int*)l, 16, 0, 0);
}

// ---------------- dequant + transpose: q[K][N] (int, zp=128), scales[K/128][N] -> wt[N][K] bf16
__global__ void dequant_t_kernel(const int* __restrict__ q,
                                 const float* __restrict__ scales,
                                 __hip_bfloat16* __restrict__ wt,
                                 int K, int N)
{
    __shared__ float tile[32][33];
    const int n0 = blockIdx.x * 32, k0 = blockIdx.y * 32;
    const int tx = threadIdx.x, ty = threadIdx.y; // (32,8)
#pragma unroll
    for (int i = 0; i < 32; i += 8) {
        int k = k0 + ty + i, n = n0 + tx;
        float s = scales[(size_t)(k >> 7) * N + n];
        tile[ty + i][tx] = (float)(q[(size_t)k * N + n] - 128) * s;
    }
    __syncthreads();
#pragma unroll
    for (int i = 0; i < 32; i += 8) {
        int n = n0 + ty + i, k = k0 + tx;
        wt[(size_t)n * K + k] = __float2bfloat16(tile[tx][ty + i]);
    }
}

// ---------------- LayerNorm: one block (256 thr) per row; writes bf16 at chunk-local row
__global__ __launch_bounds__(256)
void ln_kernel(const float* __restrict__ x, const float* __restrict__ gamma,
               const float* __restrict__ beta, __hip_bfloat16* __restrict__ hf,
               int m0)
{
    const int row = m0 + blockIdx.x;
    const float4 v = ((const float4*)(x + (size_t)row * HH))[threadIdx.x];
    float s  = v.x + v.y + v.z + v.w;
    float ss = v.x * v.x + v.y * v.y + v.z * v.z + v.w * v.w;
#pragma unroll
    for (int o = 32; o > 0; o >>= 1) { s += __shfl_down(s, o); ss += __shfl_down(ss, o); }
    __shared__ float red[8];
    const int wid = threadIdx.x >> 6, lane = threadIdx.x & 63;
    if (lane == 0) { red[wid] = s; red[4 + wid] = ss; }
    __syncthreads();
    if (threadIdx.x == 0) {
        red[0] = red[0] + red[1] + red[2] + red[3];
        red[4] = red[4] + red[5] + red[6] + red[7];
    }
    __syncthreads();
    const float mu   = red[0] * (1.f / HH);
    const float rstd = rsqrtf(red[4] * (1.f / HH) - mu * mu + 1e-5f);
    const float4 g = ((const float4*)gamma)[threadIdx.x];
    const float4 b = ((const float4*)beta)[threadIdx.x];
    float h0 = (v.x - mu) * rstd * g.x + b.x;
    float h1 = (v.y - mu) * rstd * g.y + b.y;
    float h2 = (v.z - mu) * rstd * g.z + b.z;
    float h3 = (v.w - mu) * rstd * g.w + b.w;
    __hip_bfloat16 t0 = __float2bfloat16(h0), t1 = __float2bfloat16(h1);
    __hip_bfloat16 t2 = __float2bfloat16(h2), t3 = __float2bfloat16(h3);
    ushort4 o;
    o.x = *(unsigned short*)&t0; o.y = *(unsigned short*)&t1;
    o.z = *(unsigned short*)&t2; o.w = *(unsigned short*)&t3;
    ((ushort4*)(hf + (size_t)blockIdx.x * HH))[threadIdx.x] = o;
}

// ---------------- m97-style 128x128x32 bf16 MFMA GEMM, B given transposed [N][K]
// EPI=0: out = bf16( silu(acc + bias) )            (out ld = N, bf16)
// EPI=1: out = resid + 0.5f*(acc + bias)           (out ld = N, f32)
template<int EPI>
__global__ __launch_bounds__(256, 2)
void gemm_kernel(const __hip_bfloat16* __restrict__ A,
                 const __hip_bfloat16* __restrict__ Bt,
                 const float* __restrict__ bias,
                 const float* __restrict__ resid,
                 void* __restrict__ outv,
                 int N, int K)
{
    __shared__ __align__(16) short As[128 * 32];
    __shared__ __align__(16) short Bs[128 * 32];
    const int tid  = threadIdx.x;
    const int lane = tid & 63, wid = tid >> 6;
    const int wr = wid >> 1, wc = wid & 1;
    const int lrow = lane & 15, lgrp = lane >> 4;
    const int rowA0 = blockIdx.y * 128;   // output rows
    const int colB0 = blockIdx.x * 128;   // output cols (= Bt rows)

    const int s_row = lane >> 2;          // staging: row within 16-row chunk
    const int s_col = (lane & 3) * 8;     // staging: k element offset

    f32x4 acc[4][4];
#pragma unroll
    for (int i = 0; i < 4; ++i)
#pragma unroll
        for (int j = 0; j < 4; ++j)
            acc[i][j] = f32x4{0.f, 0.f, 0.f, 0.f};

    for (int kt = 0; kt < K; kt += 32) {
#pragma unroll
        for (int c = 0; c < 2; ++c) {
            const int chunk = wid + c * 4;
            const __hip_bfloat16* ga =
                A + (size_t)(rowA0 + chunk * 16 + s_row) * K + kt + s_col;
            async_load16(ga, As + chunk * 512);
            const __hip_bfloat16* gb =
                Bt + (size_t)(colB0 + chunk * 16 + s_row) * K + kt + s_col;
            async_load16(gb, Bs + chunk * 512);
        }
        __syncthreads();
        bf16x8 aF[4], bF[4];
#pragma unroll
        for (int mi = 0; mi < 4; ++mi)
            aF[mi] = *(const bf16x8*)(As + (wr * 64 + mi * 16 + lrow) * 32 + lgrp * 8);
#pragma unroll
        for (int ni = 0; ni < 4; ++ni)
            bF[ni] = *(const bf16x8*)(Bs + (wc * 64 + ni * 16 + lrow) * 32 + lgrp * 8);
#pragma unroll
        for (int mi = 0; mi < 4; ++mi)
#pragma unroll
            for (int ni = 0; ni < 4; ++ni)
                acc[mi][ni] = __builtin_amdgcn_mfma_f32_16x16x32_bf16(
                    aF[mi], bF[ni], acc[mi][ni], 0, 0, 0);
        __syncthreads();
    }

#pragma unroll
    for (int ni = 0; ni < 4; ++ni) {
        const int col = colB0 + wc * 64 + ni * 16 + lrow;
        const float bv = bias[col];
#pragma unroll
        for (int mi = 0; mi < 4; ++mi) {
            const int row0 = rowA0 + wr * 64 + mi * 16 + lgrp * 4;
#pragma unroll
            for (int j = 0; j < 4; ++j) {
                const float v = acc[mi][ni][j] + bv;
                const size_t idx = (size_t)(row0 + j) * N + col;
                if (EPI == 0) {
                    const float sv = v / (1.f + __expf(-v));
                    ((__hip_bfloat16*)outv)[idx] = __float2bfloat16(sv);
                } else {
                    ((float*)outv)[idx] = resid[idx] + 0.5f * v;
                }
            }
        }
    }
}

extern "C" void kernel_launch(void* const* d_in, const int* in_sizes, int n_in,
                              void* d_out, int out_size, void* d_ws, size_t ws_size,
                              hipStream_t stream)
{
    const float* x      = (const float*)d_in[0];
    const float* gamma  = (const float*)d_in[1];
    const float* beta   = (const float*)d_in[2];
    const int*   fc1_q  = (const int*)d_in[3];
    const float* fc1_s  = (const float*)d_in[4];
    const float* fc1_b  = (const float*)d_in[5];
    const int*   fc2_q  = (const int*)d_in[6];
    const float* fc2_s  = (const float*)d_in[7];
    const float* fc2_b  = (const float*)d_in[8];
    float* out = (float*)d_out;

    char* ws = (char*)d_ws;
    __hip_bfloat16* w1t = (__hip_bfloat16*)ws;                            // [F][H]
    __hip_bfloat16* w2t = (__hip_bfloat16*)(ws + (size_t)FF * HH * 2);    // [H][F]
    char* dyn = ws + (size_t)2 * FF * HH * 2;                             // 16 MB in
    const size_t avail = ws_size - (size_t)2 * FF * HH * 2;

    int MC = (int)(avail / ((size_t)(HH + FF) * 2));  // rows of (hf + y) that fit
    MC = (MC / 128) * 128;
    if (MC > MTOT) MC = MTOT;
    if (MC < 128)  MC = 128;

    __hip_bfloat16* hf_c = (__hip_bfloat16*)dyn;
    __hip_bfloat16* y_c  = (__hip_bfloat16*)(dyn + (size_t)MC * HH * 2);

    // dequantize + transpose weights (once per call)
    dequant_t_kernel<<<dim3(FF / 32, HH / 32), dim3(32, 8), 0, stream>>>(
        fc1_q, fc1_s, w1t, HH, FF);
    dequant_t_kernel<<<dim3(HH / 32, FF / 32), dim3(32, 8), 0, stream>>>(
        fc2_q, fc2_s, w2t, FF, HH);

    for (int m0 = 0; m0 < MTOT; m0 += MC) {
        const int mc = (MTOT - m0 < MC) ? (MTOT - m0) : MC;
        ln_kernel<<<mc, 256, 0, stream>>>(x, gamma, beta, hf_c, m0);
        gemm_kernel<0><<<dim3(FF / 128, mc / 128), 256, 0, stream>>>(
            hf_c, w1t, fc1_b, nullptr, (void*)y_c, FF, HH);
        gemm_kernel<1><<<dim3(HH / 128, mc / 128), 256, 0, stream>>>(
            y_c, w2t, fc2_b, x + (size_t)m0 * HH, (void*)(out + (size_t)m0 * HH), HH, FF);
    }
}

// Round 2
// 361.716 us; speedup vs baseline: 1.1796x; 1.1796x over previous
//
#include <hip/hip_runtime.h>
#include <hip/hip_bf16.h>

#define HH 1024
#define FF 4096
#define MTOT (8 * 2048)

typedef __attribute__((ext_vector_type(4))) float f32x4;
typedef __attribute__((ext_vector_type(8))) short bf16x8;

__device__ inline void async_load16(const void* g, void* l) {
    __builtin_amdgcn_global_load_lds(
        (const __attribute__((address_space(1))) unsigned int*)g,
        (__attribute__((address_space(3))) unsigned int*)l, 16, 0, 0);
}
__device__ inline unsigned lds_off(void* p) {
    return (unsigned)(size_t)(__attribute__((address_space(3))) char*)p;
}
__device__ inline bf16x8 lds_read16(unsigned addr) {
    bf16x8 r;
    asm volatile("ds_read_b128 %0, %1" : "=v"(r) : "v"(addr));
    return r;
}
#define SBAR() do { asm volatile("s_barrier" ::: "memory"); __builtin_amdgcn_sched_barrier(0); } while (0)
#define WAIT_LGKM0() do { asm volatile("s_waitcnt lgkmcnt(0)" ::: "memory"); __builtin_amdgcn_sched_barrier(0); } while (0)
#define WAIT_VM4() do { asm volatile("s_waitcnt vmcnt(4)" ::: "memory"); } while (0)

// ---------------- dequant + transpose: q[K][N], scales[K/128][N] -> wt[N][K] bf16
__global__ void dequant_t_kernel(const int* __restrict__ q,
                                 const float* __restrict__ scales,
                                 __hip_bfloat16* __restrict__ wt,
                                 int K, int N)
{
    __shared__ float tile[32][33];
    const int n0 = blockIdx.x * 32, k0 = blockIdx.y * 32;
    const int tx = threadIdx.x, ty = threadIdx.y; // (32,8)
#pragma unroll
    for (int i = 0; i < 32; i += 8) {
        int k = k0 + ty + i, n = n0 + tx;
        float s = scales[(size_t)(k >> 7) * N + n];
        tile[ty + i][tx] = (float)(q[(size_t)k * N + n] - 128) * s;
    }
    __syncthreads();
#pragma unroll
    for (int i = 0; i < 32; i += 8) {
        int n = n0 + ty + i, k = k0 + tx;
        wt[(size_t)n * K + k] = __float2bfloat16(tile[tx][ty + i]);
    }
}

// ---------------- LayerNorm
__global__ __launch_bounds__(256)
void ln_kernel(const float* __restrict__ x, const float* __restrict__ gamma,
               const float* __restrict__ beta, __hip_bfloat16* __restrict__ hf,
               int m0)
{
    const int row = m0 + blockIdx.x;
    const float4 v = ((const float4*)(x + (size_t)row * HH))[threadIdx.x];
    float s  = v.x + v.y + v.z + v.w;
    float ss = v.x * v.x + v.y * v.y + v.z * v.z + v.w * v.w;
#pragma unroll
    for (int o = 32; o > 0; o >>= 1) { s += __shfl_down(s, o); ss += __shfl_down(ss, o); }
    __shared__ float red[8];
    const int wid = threadIdx.x >> 6, lane = threadIdx.x & 63;
    if (lane == 0) { red[wid] = s; red[4 + wid] = ss; }
    __syncthreads();
    if (threadIdx.x == 0) {
        red[0] = red[0] + red[1] + red[2] + red[3];
        red[4] = red[4] + red[5] + red[6] + red[7];
    }
    __syncthreads();
    const float mu   = red[0] * (1.f / HH);
    const float rstd = rsqrtf(red[4] * (1.f / HH) - mu * mu + 1e-5f);
    const float4 g = ((const float4*)gamma)[threadIdx.x];
    const float4 b = ((const float4*)beta)[threadIdx.x];
    float h0 = (v.x - mu) * rstd * g.x + b.x;
    float h1 = (v.y - mu) * rstd * g.y + b.y;
    float h2 = (v.z - mu) * rstd * g.z + b.z;
    float h3 = (v.w - mu) * rstd * g.w + b.w;
    __hip_bfloat16 t0 = __float2bfloat16(h0), t1 = __float2bfloat16(h1);
    __hip_bfloat16 t2 = __float2bfloat16(h2), t3 = __float2bfloat16(h3);
    ushort4 o;
    o.x = *(unsigned short*)&t0; o.y = *(unsigned short*)&t1;
    o.z = *(unsigned short*)&t2; o.w = *(unsigned short*)&t3;
    ((ushort4*)(hf + (size_t)blockIdx.x * HH))[threadIdx.x] = o;
}

// ---------------- 256x256 8-phase bf16 MFMA GEMM (m201-style), B given as Bt [N][K]
// EPI=0: out = bf16( silu(acc + bias) )     EPI=1: out = resid + 0.5f*(acc+bias)  (f32)
template<int EPI>
__global__ __launch_bounds__(512, 2)
void gemm256(const __hip_bfloat16* __restrict__ A,
             const __hip_bfloat16* __restrict__ Bt,
             const float* __restrict__ bias,
             const float* __restrict__ resid,
             void* __restrict__ outv,
             int N, int K, int nbx)
{
    __shared__ __align__(16) short As[2][256 * 64];   // 64 KiB
    __shared__ __align__(16) short Bs[2][256 * 64];   // 64 KiB
    const int NT = K >> 6;            // 64-wide K tiles (even: 16 or 64)

    // bijective XCD swizzle (m204)
    const int nwg = (int)gridDim.x, b = (int)blockIdx.x;
    const int q = nwg >> 3, r = nwg & 7;
    const int xcd = b & 7, pos = b >> 3;
    const int bid = (xcd < r) ? xcd * (q + 1) + pos
                              : r * (q + 1) + (xcd - r) * q + pos;
    const int bx = bid % nbx, by = bid / nbx;
    const int rowA0 = by * 256, colB0 = bx * 256;

    const int tid = (int)threadIdx.x;
    const int lane = tid & 63, wid = tid >> 6;
    const int wr = wid >> 2, wc = wid & 3;       // 2x4 wave grid
    const int lrow = lane & 15, kg = lane >> 4;
    const int swz = lrow & 7;

    // staging: thread t covers (row = base + t/8, 16B slot = t%8), source pre-inverse-swizzled
    const int srow = tid >> 3;
    const int sgs  = (tid & 7) ^ (srow & 7);
    const __hip_bfloat16* aSrc = A  + (size_t)(rowA0 + srow) * K + sgs * 8;
    const __hip_bfloat16* bSrc = Bt + (size_t)(colB0 + srow) * K + sgs * 8;
    short* aDstB = &As[0][0] + srow * 64 + (tid & 7) * 8;
    short* bDstB = &Bs[0][0] + srow * 64 + (tid & 7) * 8;

    const unsigned asB = lds_off(&As[0][0]);
    const unsigned bsB = lds_off(&Bs[0][0]);
    const unsigned k0off = (unsigned)(((0 + kg) ^ swz) << 4);   // ks=0 slot byte off
    const unsigned k1off = (unsigned)(((4 + kg) ^ swz) << 4);   // ks=1

    auto stA = [&](int buf, int t, int half) {
        const int tt = (t < NT) ? t : NT - 1;
#pragma unroll
        for (int c = 0; c < 2; ++c) {
            const int r0 = half * 128 + c * 64;
            async_load16(aSrc + (size_t)r0 * K + (size_t)tt * 64,
                         aDstB + buf * 16384 + r0 * 64);
        }
    };
    auto stB = [&](int buf, int t, int half) {
        const int tt = (t < NT) ? t : NT - 1;
#pragma unroll
        for (int c = 0; c < 2; ++c) {
            const int r0 = half * 128 + c * 64;
            async_load16(bSrc + (size_t)r0 * K + (size_t)tt * 64,
                         bDstB + buf * 16384 + r0 * 64);
        }
    };
    auto ldA = [&](bf16x8 (&d)[4][2], int buf, int mh) {
#pragma unroll
        for (int m2 = 0; m2 < 4; ++m2) {
            const unsigned ra = asB + (unsigned)(buf * 32768) +
                (unsigned)((wr * 128 + (mh * 4 + m2) * 16 + lrow) * 128);
            d[m2][0] = lds_read16(ra + k0off);
            d[m2][1] = lds_read16(ra + k1off);
        }
    };
    auto ldB = [&](bf16x8 (&d)[2][2], int buf, int nh) {
#pragma unroll
        for (int n2 = 0; n2 < 2; ++n2) {
            const unsigned ra = bsB + (unsigned)(buf * 32768) +
                (unsigned)((wc * 64 + (nh * 2 + n2) * 16 + lrow) * 128);
            d[n2][0] = lds_read16(ra + k0off);
            d[n2][1] = lds_read16(ra + k1off);
        }
    };

    f32x4 acc[8][4] = {};
    auto mf = [&](bf16x8 (&a)[4][2], bf16x8 (&bb)[2][2], int mh, int nh) {
        __builtin_amdgcn_s_setprio(1);
#pragma unroll
        for (int m2 = 0; m2 < 4; ++m2)
#pragma unroll
            for (int n2 = 0; n2 < 2; ++n2)
#pragma unroll
                for (int ks = 0; ks < 2; ++ks)
                    acc[mh * 4 + m2][nh * 2 + n2] =
                        __builtin_amdgcn_mfma_f32_16x16x32_bf16(
                            a[m2][ks], bb[n2][ks], acc[mh * 4 + m2][nh * 2 + n2], 0, 0, 0);
        __builtin_amdgcn_s_setprio(0);
    };

    // -------- prologue: tile0 (B then A) + tile1 B halves; vmcnt(4) => tile0 landed
    stB(0, 0, 0); stB(0, 0, 1); stA(0, 0, 0); stA(0, 0, 1);
    stB(1, 1, 0); stB(1, 1, 1);
    WAIT_VM4();
    SBAR();

    bf16x8 a0[4][2], a1[4][2], b0[2][2], b1[2][2];
    const int NI = NT >> 1;
    for (int i = 0; i < NI; ++i) {
        const int c = 2 * i, n = 2 * i + 1;
        // P1: quad (0,0) of tile c           stage A_buf1.H0[n]
        ldA(a0, 0, 0); ldB(b0, 0, 0);
        stA(1, n, 0);
        SBAR(); WAIT_LGKM0();
        mf(a0, b0, 0, 0);
        SBAR();
        // P2: quad (0,1)                      stage A_buf1.H1[n]
        ldB(b1, 0, 1);
        stA(1, n, 1);
        SBAR(); WAIT_LGKM0();
        mf(a0, b1, 0, 1);
        SBAR();
        // P3: quad (1,0)                      stage B_buf0.H0[c+2]
        ldA(a1, 0, 1);
        stB(0, c + 2, 0);
        SBAR(); WAIT_LGKM0();
        mf(a1, b0, 1, 0);
        SBAR();
        // P4: quad (1,1)                      stage B_buf0.H1[c+2]; counted wait
        stB(0, c + 2, 1);
        WAIT_VM4();
        SBAR();
        mf(a1, b1, 1, 1);
        SBAR();
        // P5: quad (0,0) of tile n            stage A_buf0.H0[c+2]
        ldA(a0, 1, 0); ldB(b0, 1, 0);
        stA(0, c + 2, 0);
        SBAR(); WAIT_LGKM0();
        mf(a0, b0, 0, 0);
        SBAR();
        // P6: quad (0,1)                      stage A_buf0.H1[c+2]
        ldB(b1, 1, 1);
        stA(0, c + 2, 1);
        SBAR(); WAIT_LGKM0();
        mf(a0, b1, 0, 1);
        SBAR();
        // P7: quad (1,0)                      stage B_buf1.H0[n+2]
        ldA(a1, 1, 1);
        stB(1, n + 2, 0);
        SBAR(); WAIT_LGKM0();
        mf(a1, b0, 1, 0);
        SBAR();
        // P8: quad (1,1)                      stage B_buf1.H1[n+2]; counted wait
        stB(1, n + 2, 1);
        WAIT_VM4();
        SBAR();
        mf(a1, b1, 1, 1);
        SBAR();
    }

    // -------- epilogue
#pragma unroll
    for (int ni = 0; ni < 4; ++ni) {
        const int col = colB0 + wc * 64 + ni * 16 + lrow;
        const float bv = bias[col];
#pragma unroll
        for (int mi = 0; mi < 8; ++mi) {
            const int row0 = rowA0 + wr * 128 + mi * 16 + kg * 4;
#pragma unroll
            for (int j = 0; j < 4; ++j) {
                const float v = acc[mi][ni][j] + bv;
                const size_t idx = (size_t)(row0 + j) * N + col;
                if (EPI == 0) {
                    const float sv = v / (1.f + __expf(-v));
                    ((__hip_bfloat16*)outv)[idx] = __float2bfloat16(sv);
                } else {
                    ((float*)outv)[idx] = resid[idx] + 0.5f * v;
                }
            }
        }
    }
}

extern "C" void kernel_launch(void* const* d_in, const int* in_sizes, int n_in,
                              void* d_out, int out_size, void* d_ws, size_t ws_size,
                              hipStream_t stream)
{
    const float* x      = (const float*)d_in[0];
    const float* gamma  = (const float*)d_in[1];
    const float* beta   = (const float*)d_in[2];
    const int*   fc1_q  = (const int*)d_in[3];
    const float* fc1_s  = (const float*)d_in[4];
    const float* fc1_b  = (const float*)d_in[5];
    const int*   fc2_q  = (const int*)d_in[6];
    const float* fc2_s  = (const float*)d_in[7];
    const float* fc2_b  = (const float*)d_in[8];
    float* out = (float*)d_out;

    char* ws = (char*)d_ws;
    __hip_bfloat16* w1t = (__hip_bfloat16*)ws;                            // [F][H]
    __hip_bfloat16* w2t = (__hip_bfloat16*)(ws + (size_t)FF * HH * 2);    // [H][F]
    char* dyn = ws + (size_t)2 * FF * HH * 2;
    const size_t avail = ws_size - (size_t)2 * FF * HH * 2;

    int MC = (int)(avail / ((size_t)(HH + FF) * 2));
    MC = (MC / 256) * 256;
    if (MC > MTOT) MC = MTOT;
    if (MC < 256)  MC = 256;

    __hip_bfloat16* hf_c = (__hip_bfloat16*)dyn;
    __hip_bfloat16* y_c  = (__hip_bfloat16*)(dyn + (size_t)MC * HH * 2);

    dequant_t_kernel<<<dim3(FF / 32, HH / 32), dim3(32, 8), 0, stream>>>(
        fc1_q, fc1_s, w1t, HH, FF);
    dequant_t_kernel<<<dim3(HH / 32, FF / 32), dim3(32, 8), 0, stream>>>(
        fc2_q, fc2_s, w2t, FF, HH);

    for (int m0 = 0; m0 < MTOT; m0 += MC) {
        const int mc = (MTOT - m0 < MC) ? (MTOT - m0) : MC;
        ln_kernel<<<mc, 256, 0, stream>>>(x, gamma, beta, hf_c, m0);
        gemm256<0><<<dim3((FF / 256) * (mc / 256)), 512, 0, stream>>>(
            hf_c, w1t, fc1_b, nullptr, (void*)y_c, FF, HH, FF / 256);
        gemm256<1><<<dim3((HH / 256) * (mc / 256)), 512, 0, stream>>>(
            y_c, w2t, fc2_b, x + (size_t)m0 * HH, (void*)(out + (size_t)m0 * HH),
            HH, FF, HH / 256);
    }
}